// Round 2
// baseline (466.429 us; speedup 1.0000x reference)
//
#include <hip/hip_runtime.h>

// GraphAE: 2x GCNConv encoder + 2-layer MLP decoder.
// N=50000, IN=128, HID=256, LAT=64, E=800000. fp32 in/out.
//
// R12 changes vs R11:
//  - aggx/agg64 channel-sliced 8 ways across XCDs (part = blockIdx.x & 7).
//    Each XCD gathers only a 64B (aggx) / 32B (agg64) channel slice of every
//    source row -> per-XCD working set 3.2MB/1.6MB fits the 4MB L2, so the
//    random gathers become L2 hits after first touch. R11 counters showed
//    FETCH_SIZE = 188.9MB = 8 XCDs x sizeof(xs): every XCD streamed the WHOLE
//    xs through its L2 via L3. Wave layout: 16 edge-slots x 4 lanes (aggx),
//    32 slots x 2 lanes (agg64); butterfly shfl_xor reduce across slots.
//    Same-partition blocks differ by 8 in blockIdx -> same XCD -> tiled xa/z
//    writes stay XCD-local (k-block ownership is per-partition).
//  - R11: hist/fill dst-range partitioned 8 ways (confirmed: fill 62.6us ->
//    out of top-5; WRITE_SIZE amplification killed).
// (R10: GEMM1+2 and GEMM3+4 fused via 32KB LDS frag tiles; R8: MFMA-frag-tiled
//  hi/lo bf16 planes, LDS-free coalesced frag loads.)

#define IN_CH  128
#define HIDDEN 256
#define LATENT 64

typedef unsigned short u16;
typedef unsigned int u32;
typedef __bf16 bf16x8 __attribute__((ext_vector_type(8)));
typedef float f32x4 __attribute__((ext_vector_type(4)));

static __device__ __forceinline__ float4 ld4(const float* p) {
    return *reinterpret_cast<const float4*>(p);
}
static __device__ __forceinline__ void st4(float* p, float4 v) {
    *reinterpret_cast<float4*>(p) = v;
}
static __device__ __forceinline__ void acc4(float4& a, float4 v) {
    a.x += v.x; a.y += v.y; a.z += v.z; a.w += v.w;
}

// truncating hi/lo split: hi = top16(v); lo = top16(v - hi). v-hi exact.
static __device__ __forceinline__ void split_bf16(float v, u16& hi, u16& lo) {
    u32 b = __float_as_uint(v);
    hi = (u16)(b >> 16);
    float hf = __uint_as_float(b & 0xFFFF0000u);
    lo = (u16)(__float_as_uint(v - hf) >> 16);
}

// tiled-layout offset (elements). K multiple of 8; row tiles of 16.
static __device__ __forceinline__ long tix(int row, int k, int K) {
    return ((long)(row >> 4) * (K >> 3) + (k >> 3)) * 128 + ((row & 15) << 3) + (k & 7);
}

#define MFMA3(ACC, AH, AL, BH, BL)                                             \
    ACC = __builtin_amdgcn_mfma_f32_16x16x32_bf16(AH, BH, ACC, 0, 0, 0);       \
    ACC = __builtin_amdgcn_mfma_f32_16x16x32_bf16(AH, BL, ACC, 0, 0, 0);       \
    ACC = __builtin_amdgcn_mfma_f32_16x16x32_bf16(AL, BH, ACC, 0, 0, 0);

// ---------------- graph structure kernels ----------------

// Partitioned histogram: block b handles edge chunk (b>>3), dst range (b&7).
__global__ void hist_kernel(const int* __restrict__ ei, int E,
                            int* __restrict__ counts, int nper) {
    int part = blockIdx.x & 7;
    int e = (blockIdx.x >> 3) * 256 + threadIdx.x;
    if (e >= E) return;
    int d = ei[E + e];
    if ((unsigned)(d - part * nper) < (unsigned)nper) atomicAdd(&counts[d], 1);
}

// scan1 also emits dinv[i] = rsqrt(counts[i]+1)
__global__ void scan1_kernel(const int* __restrict__ counts, int* __restrict__ rowptr,
                             int* __restrict__ blocksums, float* __restrict__ dinv, int N) {
    __shared__ int sh[256];
    int tid = threadIdx.x;
    int i = blockIdx.x * 256 + tid;
    int v = (i < N) ? counts[i] : 0;
    if (i < N) dinv[i] = rsqrtf((float)v + 1.0f);
    sh[tid] = v;
    __syncthreads();
    for (int off = 1; off < 256; off <<= 1) {
        int t = (tid >= off) ? sh[tid - off] : 0;
        __syncthreads();
        sh[tid] += t;
        __syncthreads();
    }
    if (i < N) rowptr[i] = sh[tid] - v;
    if (tid == 255) blocksums[blockIdx.x] = sh[255];
}

__global__ void scan2_kernel(const int* __restrict__ blocksums, int* __restrict__ blockoffs,
                             int* __restrict__ rowptr, int nblk, int N) {
    __shared__ int sh[256];
    int tid = threadIdx.x;
    int v = (tid < nblk) ? blocksums[tid] : 0;
    sh[tid] = v;
    __syncthreads();
    for (int off = 1; off < 256; off <<= 1) {
        int t = (tid >= off) ? sh[tid - off] : 0;
        __syncthreads();
        sh[tid] += t;
        __syncthreads();
    }
    if (tid < nblk) blockoffs[tid] = sh[tid] - v;
    if (tid == nblk - 1) rowptr[N] = sh[tid];
}

// scan3 (finalize rowptr, init nxt) + prescale xs = dinv*x, fused.
__global__ void scan3_prescale_kernel(
    int* __restrict__ rowptr, const int* __restrict__ blockoffs, int* __restrict__ next,
    const float* __restrict__ x, const float* __restrict__ dinv, float* __restrict__ xs,
    int N, int total4) {
    int i = blockIdx.x * 256 + threadIdx.x;
    if (i < N) {
        int r = rowptr[i] + blockoffs[i >> 8];
        rowptr[i] = r;
        next[i] = r;
    }
    if (i < total4) {
        float s = dinv[i >> 5];
        float4 v = ld4(&x[(long)i * 4]);
        v.x *= s; v.y *= s; v.z *= s; v.w *= s;
        st4(&xs[(long)i * 4], v);
    }
}

// Partitioned CSR fill: block b handles edge chunk (b>>3), dst range (b&7).
__global__ void fill_kernel(const int* __restrict__ ei, int E,
                            int* __restrict__ next, int* __restrict__ col, int nper) {
    int part = blockIdx.x & 7;
    int e = (blockIdx.x >> 3) * 256 + threadIdx.x;
    if (e >= E) return;
    int d = ei[E + e];
    if ((unsigned)(d - part * nper) < (unsigned)nper) {
        int s = ei[e];
        int pos = atomicAdd(&next[d], 1);
        col[pos] = s;
    }
}

// All four weights: W[K,N] fp32 -> transposed TILED hi/lo planes (rows=n).
__global__ void wsplit_all(
    const float* __restrict__ W1, const float* __restrict__ W2,
    const float* __restrict__ Wd1, const float* __restrict__ Wd2,
    u16* __restrict__ w1h, u16* __restrict__ w1l, u16* __restrict__ w2h, u16* __restrict__ w2l,
    u16* __restrict__ wd1h, u16* __restrict__ wd1l, u16* __restrict__ wd2h, u16* __restrict__ wd2l) {
    int idx = blockIdx.x * 256 + threadIdx.x;
    const float* W; u16 *H, *L; int K, N, base;
    if (idx < 32768)      { W = W1;  H = w1h;  L = w1l;  K = 128; N = 256; base = idx; }
    else if (idx < 49152) { W = W2;  H = w2h;  L = w2l;  K = 256; N = 64;  base = idx - 32768; }
    else if (idx < 65536) { W = Wd1; H = wd1h; L = wd1l; K = 64;  N = 256; base = idx - 49152; }
    else if (idx < 98304) { W = Wd2; H = wd2h; L = wd2l; K = 256; N = 128; base = idx - 65536; }
    else return;
    int k = base / N, n = base % N;
    u16 h, l;
    split_bf16(W[base], h, l);
    long o = tix(n, k, K);
    H[o] = h;
    L[o] = l;
}

// ---------------- fused encoder: zs = (relu(xa@W1+b1) @ W2) * dinv ----------------
__global__ __launch_bounds__(256) void enc_fused(
    const u16* __restrict__ xa_hi, const u16* __restrict__ xa_lo,
    const u16* __restrict__ w1h, const u16* __restrict__ w1l,
    const u16* __restrict__ w2h, const u16* __restrict__ w2l,
    const float* __restrict__ b1, const float* __restrict__ dinv,
    float* __restrict__ zs, int M) {
    __shared__ u16 o1[2][32 * 256];  // 32 KB

    const int tid = threadIdx.x;
    const int wid = tid >> 6, lane = tid & 63, quad = lane >> 4, lm = lane & 15;
    const int rt0 = blockIdx.x * 2;
    const int last_rt = (M >> 4) - 1;

    // ---- stage A: out1 = relu(xa @ W1 + b1), K=128 (KB=16, KC=4) ----
    f32x4 acc[2][4];
#pragma unroll
    for (int i = 0; i < 2; i++)
#pragma unroll
        for (int j = 0; j < 4; j++) acc[i][j] = (f32x4){0.f, 0.f, 0.f, 0.f};

#pragma unroll
    for (int kc = 0; kc < 4; kc++) {
        const int kb = kc * 4 + quad;
        bf16x8 ah[2], al[2], bh[4], bl[4];
#pragma unroll
        for (int i = 0; i < 2; i++) {
            int rt = rt0 + i; rt = rt <= last_rt ? rt : last_rt;
            long o = ((long)rt * 16 + kb) * 128 + lm * 8;
            ah[i] = *(const bf16x8*)&xa_hi[o];
            al[i] = *(const bf16x8*)&xa_lo[o];
        }
#pragma unroll
        for (int j = 0; j < 4; j++) {
            long o = ((long)(wid * 4 + j) * 16 + kb) * 128 + lm * 8;
            bh[j] = *(const bf16x8*)&w1h[o];
            bl[j] = *(const bf16x8*)&w1l[o];
        }
#pragma unroll
        for (int i = 0; i < 2; i++)
#pragma unroll
            for (int j = 0; j < 4; j++) { MFMA3(acc[i][j], ah[i], al[i], bh[j], bl[j]); }
    }

    // epilogue A -> LDS tiled (row in [0,32), k=coln in [0,256), KB=32)
#pragma unroll
    for (int i = 0; i < 2; i++)
#pragma unroll
        for (int j = 0; j < 4; j++) {
            int coln = wid * 64 + j * 16 + lm;
            float bi = b1[coln];
#pragma unroll
            for (int r = 0; r < 4; r++) {
                int row = i * 16 + quad * 4 + r;  // block-local
                float v = fmaxf(acc[i][j][r] + bi, 0.f);
                u16 h, l;
                split_bf16(v, h, l);
                int o = ((row >> 4) * 32 + (coln >> 3)) * 128 + ((row & 15) << 3) + (coln & 7);
                o1[0][o] = h;
                o1[1][o] = l;
            }
        }
    __syncthreads();

    // ---- stage B: zs = (out1 @ W2) * dinv, K=256 (KB=32, KC=8), 16 cols/wave ----
    f32x4 acc2[2];
    acc2[0] = (f32x4){0.f, 0.f, 0.f, 0.f};
    acc2[1] = (f32x4){0.f, 0.f, 0.f, 0.f};
#pragma unroll
    for (int kc = 0; kc < 8; kc++) {
        const int kb = kc * 4 + quad;
        bf16x8 ah[2], al[2], bh, bl;
#pragma unroll
        for (int i = 0; i < 2; i++) {
            int o = (i * 32 + kb) * 128 + lm * 8;
            ah[i] = *(const bf16x8*)&o1[0][o];
            al[i] = *(const bf16x8*)&o1[1][o];
        }
        {
            long o = ((long)wid * 32 + kb) * 128 + lm * 8;
            bh = *(const bf16x8*)&w2h[o];
            bl = *(const bf16x8*)&w2l[o];
        }
#pragma unroll
        for (int i = 0; i < 2; i++) { MFMA3(acc2[i], ah[i], al[i], bh, bl); }
    }
#pragma unroll
    for (int i = 0; i < 2; i++) {
        int coln = wid * 16 + lm;
#pragma unroll
        for (int r = 0; r < 4; r++) {
            int row = rt0 * 16 + i * 16 + quad * 4 + r;
            if (row < M) zs[(long)row * 64 + coln] = acc2[i][r] * dinv[row];
        }
    }
}

// ---------------- fused decoder: out = relu(z@Wd1+bd1)@Wd2 + bd2 ----------------
__global__ __launch_bounds__(256) void dec_fused(
    const u16* __restrict__ z_hi, const u16* __restrict__ z_lo,
    const u16* __restrict__ wd1h, const u16* __restrict__ wd1l,
    const u16* __restrict__ wd2h, const u16* __restrict__ wd2l,
    const float* __restrict__ bd1, const float* __restrict__ bd2,
    float* __restrict__ out, int M) {
    __shared__ u16 dsm[2][32 * 256];  // 32 KB

    const int tid = threadIdx.x;
    const int wid = tid >> 6, lane = tid & 63, quad = lane >> 4, lm = lane & 15;
    const int rt0 = blockIdx.x * 2;
    const int last_rt = (M >> 4) - 1;

    // ---- stage A: d = relu(z @ Wd1 + bd1), K=64 (KB=8, KC=2) ----
    f32x4 acc[2][4];
#pragma unroll
    for (int i = 0; i < 2; i++)
#pragma unroll
        for (int j = 0; j < 4; j++) acc[i][j] = (f32x4){0.f, 0.f, 0.f, 0.f};

#pragma unroll
    for (int kc = 0; kc < 2; kc++) {
        const int kb = kc * 4 + quad;
        bf16x8 ah[2], al[2], bh[4], bl[4];
#pragma unroll
        for (int i = 0; i < 2; i++) {
            int rt = rt0 + i; rt = rt <= last_rt ? rt : last_rt;
            long o = ((long)rt * 8 + kb) * 128 + lm * 8;
            ah[i] = *(const bf16x8*)&z_hi[o];
            al[i] = *(const bf16x8*)&z_lo[o];
        }
#pragma unroll
        for (int j = 0; j < 4; j++) {
            long o = ((long)(wid * 4 + j) * 8 + kb) * 128 + lm * 8;
            bh[j] = *(const bf16x8*)&wd1h[o];
            bl[j] = *(const bf16x8*)&wd1l[o];
        }
#pragma unroll
        for (int i = 0; i < 2; i++)
#pragma unroll
            for (int j = 0; j < 4; j++) { MFMA3(acc[i][j], ah[i], al[i], bh[j], bl[j]); }
    }

    // epilogue A -> LDS tiled
#pragma unroll
    for (int i = 0; i < 2; i++)
#pragma unroll
        for (int j = 0; j < 4; j++) {
            int coln = wid * 64 + j * 16 + lm;
            float bi = bd1[coln];
#pragma unroll
            for (int r = 0; r < 4; r++) {
                int row = i * 16 + quad * 4 + r;
                float v = fmaxf(acc[i][j][r] + bi, 0.f);
                u16 h, l;
                split_bf16(v, h, l);
                int o = ((row >> 4) * 32 + (coln >> 3)) * 128 + ((row & 15) << 3) + (coln & 7);
                dsm[0][o] = h;
                dsm[1][o] = l;
            }
        }
    __syncthreads();

    // ---- stage B: out = d @ Wd2 + bd2, K=256 (KB=32, KC=8), 32 cols/wave ----
    f32x4 acc2[2][2];
#pragma unroll
    for (int i = 0; i < 2; i++)
#pragma unroll
        for (int j = 0; j < 2; j++) acc2[i][j] = (f32x4){0.f, 0.f, 0.f, 0.f};
#pragma unroll
    for (int kc = 0; kc < 8; kc++) {
        const int kb = kc * 4 + quad;
        bf16x8 ah[2], al[2], bh[2], bl[2];
#pragma unroll
        for (int i = 0; i < 2; i++) {
            int o = (i * 32 + kb) * 128 + lm * 8;
            ah[i] = *(const bf16x8*)&dsm[0][o];
            al[i] = *(const bf16x8*)&dsm[1][o];
        }
#pragma unroll
        for (int j = 0; j < 2; j++) {
            long o = ((long)(wid * 2 + j) * 32 + kb) * 128 + lm * 8;
            bh[j] = *(const bf16x8*)&wd2h[o];
            bl[j] = *(const bf16x8*)&wd2l[o];
        }
#pragma unroll
        for (int i = 0; i < 2; i++)
#pragma unroll
            for (int j = 0; j < 2; j++) { MFMA3(acc2[i][j], ah[i], al[i], bh[j], bl[j]); }
    }
#pragma unroll
    for (int i = 0; i < 2; i++)
#pragma unroll
        for (int j = 0; j < 2; j++) {
            int coln = wid * 32 + j * 16 + lm;
            float bi = bd2[coln];
#pragma unroll
            for (int r = 0; r < 4; r++) {
                int row = rt0 * 16 + i * 16 + quad * 4 + r;
                if (row < M) out[(long)row * 128 + coln] = acc2[i][j][r] + bi;
            }
        }
}

// ---------------- aggregation kernels ----------------

// AGGX (channel-sliced): partition p = blockIdx.x & 7 owns channels
// [p*16, p*16+16). Per-XCD gather working set = 50000*64B = 3.2MB -> L2
// resident. Wave = 1 node, 16 edge-slots x 4 lanes x float4.
__global__ __launch_bounds__(256) void aggx_kernel(
    const float* __restrict__ xs, const int* __restrict__ rowptr, const int* __restrict__ col,
    const float* __restrict__ dinv, u16* __restrict__ xahi, u16* __restrict__ xalo, int N) {
    const int part = blockIdx.x & 7;
    const int wid = threadIdx.x >> 6;
    const int lane = threadIdx.x & 63;
    const int node = (blockIdx.x >> 3) * 4 + wid;
    if (node >= N) return;
    const int slot = lane >> 2;                 // 16 edge slots
    const int c = part * 16 + (lane & 3) * 4;   // channel offset (float4)

    float4 a = make_float4(0.f, 0.f, 0.f, 0.f);
    float4 b = a;
    if (slot == 0) a = ld4(&xs[(long)node * 128 + c]);  // self-loop term

    const int beg = rowptr[node];
    const int end = rowptr[node + 1];
    int cb = beg + slot;
    for (; cb + 16 < end; cb += 32) {
        int s0 = col[cb];
        int s1 = col[cb + 16];
        float4 v0 = ld4(&xs[(long)s0 * 128 + c]);
        float4 v1 = ld4(&xs[(long)s1 * 128 + c]);
        acc4(a, v0);
        acc4(b, v1);
    }
    if (cb < end) acc4(a, ld4(&xs[(long)col[cb] * 128 + c]));
    acc4(a, b);

    // butterfly reduce across the 16 slots (stride 4,8,16,32)
#pragma unroll
    for (int m = 4; m <= 32; m <<= 1) {
        a.x += __shfl_xor(a.x, m);
        a.y += __shfl_xor(a.y, m);
        a.z += __shfl_xor(a.z, m);
        a.w += __shfl_xor(a.w, m);
    }
    if (slot == 0) {
        float di = dinv[node];
        a.x *= di; a.y *= di; a.z *= di; a.w *= di;
        ushort4 h, l;
        split_bf16(a.x, h.x, l.x);
        split_bf16(a.y, h.y, l.y);
        split_bf16(a.z, h.z, l.z);
        split_bf16(a.w, h.w, l.w);
        long o = tix(node, c, 128);
        *(ushort4*)&xahi[o] = h;
        *(ushort4*)&xalo[o] = l;
    }
}

// AGG2 (channel-sliced): partition p = blockIdx.x & 7 owns channels
// [p*8, p*8+8). Per-XCD working set = 50000*32B = 1.6MB. Wave = 1 node,
// 32 edge-slots x 2 lanes x float4.
__global__ __launch_bounds__(256) void agg64_kernel(
    const float* __restrict__ zs, const int* __restrict__ rowptr, const int* __restrict__ col,
    const float* __restrict__ dinv, const float* __restrict__ bias,
    u16* __restrict__ zhi, u16* __restrict__ zlo, int N) {
    const int part = blockIdx.x & 7;
    const int wid = threadIdx.x >> 6;
    const int lane = threadIdx.x & 63;
    const int node = (blockIdx.x >> 3) * 4 + wid;
    if (node >= N) return;
    const int slot = lane >> 1;                // 32 edge slots
    const int c = part * 8 + (lane & 1) * 4;   // channel offset (float4)

    float4 a = make_float4(0.f, 0.f, 0.f, 0.f);
    float4 b = a;
    if (slot == 0) a = ld4(&zs[(long)node * 64 + c]);  // self term

    const int beg = rowptr[node];
    const int end = rowptr[node + 1];
    int cb = beg + slot;
    for (; cb + 32 < end; cb += 64) {
        int s0 = col[cb];
        int s1 = col[cb + 32];
        float4 v0 = ld4(&zs[(long)s0 * 64 + c]);
        float4 v1 = ld4(&zs[(long)s1 * 64 + c]);
        acc4(a, v0);
        acc4(b, v1);
    }
    if (cb < end) acc4(a, ld4(&zs[(long)col[cb] * 64 + c]));
    acc4(a, b);

    // butterfly reduce across the 32 slots (stride 2,4,8,16,32)
#pragma unroll
    for (int m = 2; m <= 32; m <<= 1) {
        a.x += __shfl_xor(a.x, m);
        a.y += __shfl_xor(a.y, m);
        a.z += __shfl_xor(a.z, m);
        a.w += __shfl_xor(a.w, m);
    }
    if (slot == 0) {
        float di = dinv[node];
        float4 bi = ld4(&bias[c]);
        a.x = a.x * di + bi.x;
        a.y = a.y * di + bi.y;
        a.z = a.z * di + bi.z;
        a.w = a.w * di + bi.w;
        ushort4 h, l;
        split_bf16(a.x, h.x, l.x);
        split_bf16(a.y, h.y, l.y);
        split_bf16(a.z, h.z, l.z);
        split_bf16(a.w, h.w, l.w);
        long o = tix(node, c, 64);
        *(ushort4*)&zhi[o] = h;
        *(ushort4*)&zlo[o] = l;
    }
}

// ---------------- launch ----------------

extern "C" void kernel_launch(void* const* d_in, const int* in_sizes, int n_in,
                              void* d_out, int out_size, void* d_ws, size_t ws_size,
                              hipStream_t stream) {
    const float* x        = (const float*)d_in[0];
    const int* ei         = (const int*)d_in[1];   // int32 (harness integer convention)
    const float* W1       = (const float*)d_in[2];
    const float* b1       = (const float*)d_in[3];
    const float* W2       = (const float*)d_in[4];
    const float* b2       = (const float*)d_in[5];
    const float* Wd1      = (const float*)d_in[6];
    const float* bd1      = (const float*)d_in[7];
    const float* Wd2      = (const float*)d_in[8];
    const float* bd2      = (const float*)d_in[9];
    float* out            = (float*)d_out;

    const int N = in_sizes[0] / IN_CH;   // 50000 (multiple of 16)
    const int E = in_sizes[1] / 2;       // 800000

    char* p = (char*)d_ws;
    auto alloc = [&](size_t bytes) {
        char* r = p;
        p += (bytes + 255) & ~(size_t)255;
        return r;
    };
    int*   counts    = (int*)  alloc((size_t)(N + 1) * 4);
    int*   rowptr    = (int*)  alloc((size_t)(N + 1) * 4);
    int*   nxt       = (int*)  alloc((size_t)N * 4);
    int*   blocksums = (int*)  alloc(256 * 4);
    int*   blockoffs = (int*)  alloc(256 * 4);
    float* dinv      = (float*)alloc((size_t)N * 4);
    int*   col       = (int*)  alloc((size_t)E * 4);
    float* xs        = (float*)alloc((size_t)N * IN_CH * 4);
    u16*   xa_hi     = (u16*)  alloc((size_t)N * IN_CH * 2);
    u16*   xa_lo     = (u16*)  alloc((size_t)N * IN_CH * 2);
    float* zs        = (float*)alloc((size_t)N * LATENT * 4);
    u16*   z_hi      = (u16*)  alloc((size_t)N * LATENT * 2);
    u16*   z_lo      = (u16*)  alloc((size_t)N * LATENT * 2);
    u16*   w1t_hi    = (u16*)  alloc((size_t)IN_CH * HIDDEN * 2);
    u16*   w1t_lo    = (u16*)  alloc((size_t)IN_CH * HIDDEN * 2);
    u16*   w2t_hi    = (u16*)  alloc((size_t)HIDDEN * LATENT * 2);
    u16*   w2t_lo    = (u16*)  alloc((size_t)HIDDEN * LATENT * 2);
    u16*   wd1t_hi   = (u16*)  alloc((size_t)LATENT * HIDDEN * 2);
    u16*   wd1t_lo   = (u16*)  alloc((size_t)LATENT * HIDDEN * 2);
    u16*   wd2t_hi   = (u16*)  alloc((size_t)HIDDEN * IN_CH * 2);
    u16*   wd2t_lo   = (u16*)  alloc((size_t)HIDDEN * IN_CH * 2);

    const int nblk = (N + 255) / 256;
    const int total4 = N * (IN_CH / 4);
    const int chunks = (E + 255) / 256;          // edge chunks of 256
    const int nper = (N + 7) / 8;                // dst-range width per partition
    const int nb4 = (N + 3) / 4;                 // node blocks (4 nodes/block)

    hipMemsetAsync(counts, 0, (size_t)(N + 1) * 4, stream);
    hist_kernel<<<chunks * 8, 256, 0, stream>>>(ei, E, counts, nper);
    scan1_kernel<<<nblk, 256, 0, stream>>>(counts, rowptr, blocksums, dinv, N);
    scan2_kernel<<<1, 256, 0, stream>>>(blocksums, blockoffs, rowptr, nblk, N);
    scan3_prescale_kernel<<<(total4 + 255) / 256, 256, 0, stream>>>(
        rowptr, blockoffs, nxt, x, dinv, xs, N, total4);
    fill_kernel<<<chunks * 8, 256, 0, stream>>>(ei, E, nxt, col, nper);
    wsplit_all<<<384, 256, 0, stream>>>(W1, W2, Wd1, Wd2,
                                        w1t_hi, w1t_lo, w2t_hi, w2t_lo,
                                        wd1t_hi, wd1t_lo, wd2t_hi, wd2t_lo);

    // AGGX: xa = D^-1/2 A^ D^-1/2 X (channel-sliced, tiled split out)
    aggx_kernel<<<nb4 * 8, 256, 0, stream>>>(xs, rowptr, col, dinv, xa_hi, xa_lo, N);

    const int fblk = (N + 31) / 32;  // 1563

    // enc_fused: zs = (relu(xa@W1+b1) @ W2) * dinv
    enc_fused<<<fblk, 256, 0, stream>>>(xa_hi, xa_lo, w1t_hi, w1t_lo,
                                        w2t_hi, w2t_lo, b1, dinv, zs, N);
    // AGG2: z = dinv*(sum zs) + b2 -> tiled split (channel-sliced)
    agg64_kernel<<<nb4 * 8, 256, 0, stream>>>(zs, rowptr, col, dinv, b2, z_hi, z_lo, N);
    // dec_fused: out = relu(z@Wd1+bd1) @ Wd2 + bd2
    dec_fused<<<fblk, 256, 0, stream>>>(z_hi, z_lo, wd1t_hi, wd1t_lo,
                                        wd2t_hi, wd2t_lo, bd1, bd2, out, N);
}

// Round 3
// 317.450 us; speedup vs baseline: 1.4693x; 1.4693x over previous
//
#include <hip/hip_runtime.h>

// GraphAE: 2x GCNConv encoder + 2-layer MLP decoder.
// N=50000, IN=128, HID=256, LAT=64, E=800000. fp32 in/out.
//
// R13 changes vs R12:
//  - REVERT channel-sliced agg (R12 regression: FETCH unchanged 192MB because
//    64B slices still pull 128B L2 lines -> 6.4MB/XCD footprint still > 4MB
//    L2; meanwhile 8x duplicated edge-walk made it issue-bound, VALUBusy 57%,
//    134us). Back to R11 layout: wave = 1 node, full row per gather.
//  - Deepened MLP: aggx 8 loads/lane in flight (8 accumulators, 16 edges
//    concurrent per wave); agg64 4 loads/lane (16 edges concurrent). R11 was
//    4/2-deep with VALUBusy only 22% -> latency-bound hypothesis.
//  - R11: hist/fill dst-range partitioned 8 ways (confirmed win).
// (R10: GEMM1+2 and GEMM3+4 fused via 32KB LDS frag tiles; R8: MFMA-frag-tiled
//  hi/lo bf16 planes, LDS-free coalesced frag loads.)

#define IN_CH  128
#define HIDDEN 256
#define LATENT 64

typedef unsigned short u16;
typedef unsigned int u32;
typedef __bf16 bf16x8 __attribute__((ext_vector_type(8)));
typedef float f32x4 __attribute__((ext_vector_type(4)));

static __device__ __forceinline__ float4 ld4(const float* p) {
    return *reinterpret_cast<const float4*>(p);
}
static __device__ __forceinline__ void st4(float* p, float4 v) {
    *reinterpret_cast<float4*>(p) = v;
}
static __device__ __forceinline__ void acc4(float4& a, float4 v) {
    a.x += v.x; a.y += v.y; a.z += v.z; a.w += v.w;
}

// truncating hi/lo split: hi = top16(v); lo = top16(v - hi). v-hi exact.
static __device__ __forceinline__ void split_bf16(float v, u16& hi, u16& lo) {
    u32 b = __float_as_uint(v);
    hi = (u16)(b >> 16);
    float hf = __uint_as_float(b & 0xFFFF0000u);
    lo = (u16)(__float_as_uint(v - hf) >> 16);
}

// tiled-layout offset (elements). K multiple of 8; row tiles of 16.
static __device__ __forceinline__ long tix(int row, int k, int K) {
    return ((long)(row >> 4) * (K >> 3) + (k >> 3)) * 128 + ((row & 15) << 3) + (k & 7);
}

#define MFMA3(ACC, AH, AL, BH, BL)                                             \
    ACC = __builtin_amdgcn_mfma_f32_16x16x32_bf16(AH, BH, ACC, 0, 0, 0);       \
    ACC = __builtin_amdgcn_mfma_f32_16x16x32_bf16(AH, BL, ACC, 0, 0, 0);       \
    ACC = __builtin_amdgcn_mfma_f32_16x16x32_bf16(AL, BH, ACC, 0, 0, 0);

// ---------------- graph structure kernels ----------------

// Partitioned histogram: block b handles edge chunk (b>>3), dst range (b&7).
__global__ void hist_kernel(const int* __restrict__ ei, int E,
                            int* __restrict__ counts, int nper) {
    int part = blockIdx.x & 7;
    int e = (blockIdx.x >> 3) * 256 + threadIdx.x;
    if (e >= E) return;
    int d = ei[E + e];
    if ((unsigned)(d - part * nper) < (unsigned)nper) atomicAdd(&counts[d], 1);
}

// scan1 also emits dinv[i] = rsqrt(counts[i]+1)
__global__ void scan1_kernel(const int* __restrict__ counts, int* __restrict__ rowptr,
                             int* __restrict__ blocksums, float* __restrict__ dinv, int N) {
    __shared__ int sh[256];
    int tid = threadIdx.x;
    int i = blockIdx.x * 256 + tid;
    int v = (i < N) ? counts[i] : 0;
    if (i < N) dinv[i] = rsqrtf((float)v + 1.0f);
    sh[tid] = v;
    __syncthreads();
    for (int off = 1; off < 256; off <<= 1) {
        int t = (tid >= off) ? sh[tid - off] : 0;
        __syncthreads();
        sh[tid] += t;
        __syncthreads();
    }
    if (i < N) rowptr[i] = sh[tid] - v;
    if (tid == 255) blocksums[blockIdx.x] = sh[255];
}

__global__ void scan2_kernel(const int* __restrict__ blocksums, int* __restrict__ blockoffs,
                             int* __restrict__ rowptr, int nblk, int N) {
    __shared__ int sh[256];
    int tid = threadIdx.x;
    int v = (tid < nblk) ? blocksums[tid] : 0;
    sh[tid] = v;
    __syncthreads();
    for (int off = 1; off < 256; off <<= 1) {
        int t = (tid >= off) ? sh[tid - off] : 0;
        __syncthreads();
        sh[tid] += t;
        __syncthreads();
    }
    if (tid < nblk) blockoffs[tid] = sh[tid] - v;
    if (tid == nblk - 1) rowptr[N] = sh[tid];
}

// scan3 (finalize rowptr, init nxt) + prescale xs = dinv*x, fused.
__global__ void scan3_prescale_kernel(
    int* __restrict__ rowptr, const int* __restrict__ blockoffs, int* __restrict__ next,
    const float* __restrict__ x, const float* __restrict__ dinv, float* __restrict__ xs,
    int N, int total4) {
    int i = blockIdx.x * 256 + threadIdx.x;
    if (i < N) {
        int r = rowptr[i] + blockoffs[i >> 8];
        rowptr[i] = r;
        next[i] = r;
    }
    if (i < total4) {
        float s = dinv[i >> 5];
        float4 v = ld4(&x[(long)i * 4]);
        v.x *= s; v.y *= s; v.z *= s; v.w *= s;
        st4(&xs[(long)i * 4], v);
    }
}

// Partitioned CSR fill: block b handles edge chunk (b>>3), dst range (b&7).
__global__ void fill_kernel(const int* __restrict__ ei, int E,
                            int* __restrict__ next, int* __restrict__ col, int nper) {
    int part = blockIdx.x & 7;
    int e = (blockIdx.x >> 3) * 256 + threadIdx.x;
    if (e >= E) return;
    int d = ei[E + e];
    if ((unsigned)(d - part * nper) < (unsigned)nper) {
        int s = ei[e];
        int pos = atomicAdd(&next[d], 1);
        col[pos] = s;
    }
}

// All four weights: W[K,N] fp32 -> transposed TILED hi/lo planes (rows=n).
__global__ void wsplit_all(
    const float* __restrict__ W1, const float* __restrict__ W2,
    const float* __restrict__ Wd1, const float* __restrict__ Wd2,
    u16* __restrict__ w1h, u16* __restrict__ w1l, u16* __restrict__ w2h, u16* __restrict__ w2l,
    u16* __restrict__ wd1h, u16* __restrict__ wd1l, u16* __restrict__ wd2h, u16* __restrict__ wd2l) {
    int idx = blockIdx.x * 256 + threadIdx.x;
    const float* W; u16 *H, *L; int K, N, base;
    if (idx < 32768)      { W = W1;  H = w1h;  L = w1l;  K = 128; N = 256; base = idx; }
    else if (idx < 49152) { W = W2;  H = w2h;  L = w2l;  K = 256; N = 64;  base = idx - 32768; }
    else if (idx < 65536) { W = Wd1; H = wd1h; L = wd1l; K = 64;  N = 256; base = idx - 49152; }
    else if (idx < 98304) { W = Wd2; H = wd2h; L = wd2l; K = 256; N = 128; base = idx - 65536; }
    else return;
    int k = base / N, n = base % N;
    u16 h, l;
    split_bf16(W[base], h, l);
    long o = tix(n, k, K);
    H[o] = h;
    L[o] = l;
}

// ---------------- fused encoder: zs = (relu(xa@W1+b1) @ W2) * dinv ----------------
__global__ __launch_bounds__(256) void enc_fused(
    const u16* __restrict__ xa_hi, const u16* __restrict__ xa_lo,
    const u16* __restrict__ w1h, const u16* __restrict__ w1l,
    const u16* __restrict__ w2h, const u16* __restrict__ w2l,
    const float* __restrict__ b1, const float* __restrict__ dinv,
    float* __restrict__ zs, int M) {
    __shared__ u16 o1[2][32 * 256];  // 32 KB

    const int tid = threadIdx.x;
    const int wid = tid >> 6, lane = tid & 63, quad = lane >> 4, lm = lane & 15;
    const int rt0 = blockIdx.x * 2;
    const int last_rt = (M >> 4) - 1;

    // ---- stage A: out1 = relu(xa @ W1 + b1), K=128 (KB=16, KC=4) ----
    f32x4 acc[2][4];
#pragma unroll
    for (int i = 0; i < 2; i++)
#pragma unroll
        for (int j = 0; j < 4; j++) acc[i][j] = (f32x4){0.f, 0.f, 0.f, 0.f};

#pragma unroll
    for (int kc = 0; kc < 4; kc++) {
        const int kb = kc * 4 + quad;
        bf16x8 ah[2], al[2], bh[4], bl[4];
#pragma unroll
        for (int i = 0; i < 2; i++) {
            int rt = rt0 + i; rt = rt <= last_rt ? rt : last_rt;
            long o = ((long)rt * 16 + kb) * 128 + lm * 8;
            ah[i] = *(const bf16x8*)&xa_hi[o];
            al[i] = *(const bf16x8*)&xa_lo[o];
        }
#pragma unroll
        for (int j = 0; j < 4; j++) {
            long o = ((long)(wid * 4 + j) * 16 + kb) * 128 + lm * 8;
            bh[j] = *(const bf16x8*)&w1h[o];
            bl[j] = *(const bf16x8*)&w1l[o];
        }
#pragma unroll
        for (int i = 0; i < 2; i++)
#pragma unroll
            for (int j = 0; j < 4; j++) { MFMA3(acc[i][j], ah[i], al[i], bh[j], bl[j]); }
    }

    // epilogue A -> LDS tiled (row in [0,32), k=coln in [0,256), KB=32)
#pragma unroll
    for (int i = 0; i < 2; i++)
#pragma unroll
        for (int j = 0; j < 4; j++) {
            int coln = wid * 64 + j * 16 + lm;
            float bi = b1[coln];
#pragma unroll
            for (int r = 0; r < 4; r++) {
                int row = i * 16 + quad * 4 + r;  // block-local
                float v = fmaxf(acc[i][j][r] + bi, 0.f);
                u16 h, l;
                split_bf16(v, h, l);
                int o = ((row >> 4) * 32 + (coln >> 3)) * 128 + ((row & 15) << 3) + (coln & 7);
                o1[0][o] = h;
                o1[1][o] = l;
            }
        }
    __syncthreads();

    // ---- stage B: zs = (out1 @ W2) * dinv, K=256 (KB=32, KC=8), 16 cols/wave ----
    f32x4 acc2[2];
    acc2[0] = (f32x4){0.f, 0.f, 0.f, 0.f};
    acc2[1] = (f32x4){0.f, 0.f, 0.f, 0.f};
#pragma unroll
    for (int kc = 0; kc < 8; kc++) {
        const int kb = kc * 4 + quad;
        bf16x8 ah[2], al[2], bh, bl;
#pragma unroll
        for (int i = 0; i < 2; i++) {
            int o = (i * 32 + kb) * 128 + lm * 8;
            ah[i] = *(const bf16x8*)&o1[0][o];
            al[i] = *(const bf16x8*)&o1[1][o];
        }
        {
            long o = ((long)wid * 32 + kb) * 128 + lm * 8;
            bh = *(const bf16x8*)&w2h[o];
            bl = *(const bf16x8*)&w2l[o];
        }
#pragma unroll
        for (int i = 0; i < 2; i++) { MFMA3(acc2[i], ah[i], al[i], bh, bl); }
    }
#pragma unroll
    for (int i = 0; i < 2; i++) {
        int coln = wid * 16 + lm;
#pragma unroll
        for (int r = 0; r < 4; r++) {
            int row = rt0 * 16 + i * 16 + quad * 4 + r;
            if (row < M) zs[(long)row * 64 + coln] = acc2[i][r] * dinv[row];
        }
    }
}

// ---------------- fused decoder: out = relu(z@Wd1+bd1)@Wd2 + bd2 ----------------
__global__ __launch_bounds__(256) void dec_fused(
    const u16* __restrict__ z_hi, const u16* __restrict__ z_lo,
    const u16* __restrict__ wd1h, const u16* __restrict__ wd1l,
    const u16* __restrict__ wd2h, const u16* __restrict__ wd2l,
    const float* __restrict__ bd1, const float* __restrict__ bd2,
    float* __restrict__ out, int M) {
    __shared__ u16 dsm[2][32 * 256];  // 32 KB

    const int tid = threadIdx.x;
    const int wid = tid >> 6, lane = tid & 63, quad = lane >> 4, lm = lane & 15;
    const int rt0 = blockIdx.x * 2;
    const int last_rt = (M >> 4) - 1;

    // ---- stage A: d = relu(z @ Wd1 + bd1), K=64 (KB=8, KC=2) ----
    f32x4 acc[2][4];
#pragma unroll
    for (int i = 0; i < 2; i++)
#pragma unroll
        for (int j = 0; j < 4; j++) acc[i][j] = (f32x4){0.f, 0.f, 0.f, 0.f};

#pragma unroll
    for (int kc = 0; kc < 2; kc++) {
        const int kb = kc * 4 + quad;
        bf16x8 ah[2], al[2], bh[4], bl[4];
#pragma unroll
        for (int i = 0; i < 2; i++) {
            int rt = rt0 + i; rt = rt <= last_rt ? rt : last_rt;
            long o = ((long)rt * 8 + kb) * 128 + lm * 8;
            ah[i] = *(const bf16x8*)&z_hi[o];
            al[i] = *(const bf16x8*)&z_lo[o];
        }
#pragma unroll
        for (int j = 0; j < 4; j++) {
            long o = ((long)(wid * 4 + j) * 8 + kb) * 128 + lm * 8;
            bh[j] = *(const bf16x8*)&wd1h[o];
            bl[j] = *(const bf16x8*)&wd1l[o];
        }
#pragma unroll
        for (int i = 0; i < 2; i++)
#pragma unroll
            for (int j = 0; j < 4; j++) { MFMA3(acc[i][j], ah[i], al[i], bh[j], bl[j]); }
    }

    // epilogue A -> LDS tiled
#pragma unroll
    for (int i = 0; i < 2; i++)
#pragma unroll
        for (int j = 0; j < 4; j++) {
            int coln = wid * 64 + j * 16 + lm;
            float bi = bd1[coln];
#pragma unroll
            for (int r = 0; r < 4; r++) {
                int row = i * 16 + quad * 4 + r;
                float v = fmaxf(acc[i][j][r] + bi, 0.f);
                u16 h, l;
                split_bf16(v, h, l);
                int o = ((row >> 4) * 32 + (coln >> 3)) * 128 + ((row & 15) << 3) + (coln & 7);
                dsm[0][o] = h;
                dsm[1][o] = l;
            }
        }
    __syncthreads();

    // ---- stage B: out = d @ Wd2 + bd2, K=256 (KB=32, KC=8), 32 cols/wave ----
    f32x4 acc2[2][2];
#pragma unroll
    for (int i = 0; i < 2; i++)
#pragma unroll
        for (int j = 0; j < 2; j++) acc2[i][j] = (f32x4){0.f, 0.f, 0.f, 0.f};
#pragma unroll
    for (int kc = 0; kc < 8; kc++) {
        const int kb = kc * 4 + quad;
        bf16x8 ah[2], al[2], bh[2], bl[2];
#pragma unroll
        for (int i = 0; i < 2; i++) {
            int o = (i * 32 + kb) * 128 + lm * 8;
            ah[i] = *(const bf16x8*)&dsm[0][o];
            al[i] = *(const bf16x8*)&dsm[1][o];
        }
#pragma unroll
        for (int j = 0; j < 2; j++) {
            long o = ((long)(wid * 2 + j) * 32 + kb) * 128 + lm * 8;
            bh[j] = *(const bf16x8*)&wd2h[o];
            bl[j] = *(const bf16x8*)&wd2l[o];
        }
#pragma unroll
        for (int i = 0; i < 2; i++)
#pragma unroll
            for (int j = 0; j < 2; j++) { MFMA3(acc2[i][j], ah[i], al[i], bh[j], bl[j]); }
    }
#pragma unroll
    for (int i = 0; i < 2; i++)
#pragma unroll
        for (int j = 0; j < 2; j++) {
            int coln = wid * 32 + j * 16 + lm;
            float bi = bd2[coln];
#pragma unroll
            for (int r = 0; r < 4; r++) {
                int row = rt0 * 16 + i * 16 + quad * 4 + r;
                if (row < M) out[(long)row * 128 + coln] = acc2[i][j][r] + bi;
            }
        }
}

// ---------------- aggregation kernels ----------------

// AGGX: xa[i] = dinv[i]*(xs[i] + sum_in xs[s]); writes TILED hi/lo planes.
// Wave = 1 node, 2 edge-slots x 32 lanes (full 512B row per slot).
// 8-deep load pipeline (8 accumulators) to cover L2/L3 gather latency.
__global__ __launch_bounds__(256) void aggx_kernel(
    const float* __restrict__ xs, const int* __restrict__ rowptr, const int* __restrict__ col,
    const float* __restrict__ dinv, u16* __restrict__ xahi, u16* __restrict__ xalo, int N) {
    int wid = threadIdx.x >> 6;
    int lane = threadIdx.x & 63;
    int node = blockIdx.x * 4 + wid;
    if (node >= N) return;
    int slot = lane >> 5;
    int c = (lane & 31) * 4;

    float4 a0 = make_float4(0.f, 0.f, 0.f, 0.f);
    float4 a1 = a0, a2 = a0, a3 = a0, a4 = a0, a5 = a0, a6 = a0, a7 = a0;
    if (slot == 0) a0 = ld4(&xs[(long)node * 128 + c]);

    int beg = rowptr[node];
    int end = rowptr[node + 1];
    for (int cb = beg; cb < end; cb += 64) {
        int cnt = min(64, end - cb);
        int cv = (lane < cnt) ? col[cb + lane] : 0;
        int full = cnt >> 1;
        int trips = (cnt + 1) >> 1;
        int t = 0;
        for (; t + 8 <= full; t += 8) {
            int j = slot + 2 * t;
            int s0 = __shfl(cv, j);
            int s1 = __shfl(cv, j + 2);
            int s2 = __shfl(cv, j + 4);
            int s3 = __shfl(cv, j + 6);
            int s4 = __shfl(cv, j + 8);
            int s5 = __shfl(cv, j + 10);
            int s6 = __shfl(cv, j + 12);
            int s7 = __shfl(cv, j + 14);
            float4 v0 = ld4(&xs[(long)s0 * 128 + c]);
            float4 v1 = ld4(&xs[(long)s1 * 128 + c]);
            float4 v2 = ld4(&xs[(long)s2 * 128 + c]);
            float4 v3 = ld4(&xs[(long)s3 * 128 + c]);
            float4 v4 = ld4(&xs[(long)s4 * 128 + c]);
            float4 v5 = ld4(&xs[(long)s5 * 128 + c]);
            float4 v6 = ld4(&xs[(long)s6 * 128 + c]);
            float4 v7 = ld4(&xs[(long)s7 * 128 + c]);
            acc4(a0, v0); acc4(a1, v1); acc4(a2, v2); acc4(a3, v3);
            acc4(a4, v4); acc4(a5, v5); acc4(a6, v6); acc4(a7, v7);
        }
        for (; t + 4 <= full; t += 4) {
            int j = slot + 2 * t;
            int s0 = __shfl(cv, j);
            int s1 = __shfl(cv, j + 2);
            int s2 = __shfl(cv, j + 4);
            int s3 = __shfl(cv, j + 6);
            float4 v0 = ld4(&xs[(long)s0 * 128 + c]);
            float4 v1 = ld4(&xs[(long)s1 * 128 + c]);
            float4 v2 = ld4(&xs[(long)s2 * 128 + c]);
            float4 v3 = ld4(&xs[(long)s3 * 128 + c]);
            acc4(a0, v0); acc4(a1, v1); acc4(a2, v2); acc4(a3, v3);
        }
        for (; t < trips; t++) {
            int j = slot + 2 * t;
            bool p = j < cnt;
            int s = __shfl(cv, p ? j : 0);
            if (p) acc4(a0, ld4(&xs[(long)s * 128 + c]));
        }
    }
    acc4(a0, a1); acc4(a2, a3); acc4(a4, a5); acc4(a6, a7);
    acc4(a0, a2); acc4(a4, a6); acc4(a0, a4);
    a0.x += __shfl_xor(a0.x, 32);
    a0.y += __shfl_xor(a0.y, 32);
    a0.z += __shfl_xor(a0.z, 32);
    a0.w += __shfl_xor(a0.w, 32);
    if (slot == 0) {
        float di = dinv[node];
        a0.x *= di; a0.y *= di; a0.z *= di; a0.w *= di;
        ushort4 h, l;
        split_bf16(a0.x, h.x, l.x);
        split_bf16(a0.y, h.y, l.y);
        split_bf16(a0.z, h.z, l.z);
        split_bf16(a0.w, h.w, l.w);
        long o = tix(node, c, 128);
        *(ushort4*)&xahi[o] = h;
        *(ushort4*)&xalo[o] = l;
    }
}

// AGG2: z[i] = dinv[i]*(zs[i] + sum_in zs[s]) + b2; writes TILED hi/lo planes.
// Wave = 1 node, 4 edge-slots x 16 lanes (256B row per slot). 4-deep pipeline.
__global__ __launch_bounds__(256) void agg64_kernel(
    const float* __restrict__ zs, const int* __restrict__ rowptr, const int* __restrict__ col,
    const float* __restrict__ dinv, const float* __restrict__ bias,
    u16* __restrict__ zhi, u16* __restrict__ zlo, int N) {
    int wid = threadIdx.x >> 6;
    int lane = threadIdx.x & 63;
    int node = blockIdx.x * 4 + wid;
    if (node >= N) return;
    int slot = lane >> 4;
    int c = (lane & 15) * 4;

    float4 a0 = make_float4(0.f, 0.f, 0.f, 0.f);
    float4 a1 = a0, a2 = a0, a3 = a0;
    if (slot == 0) a0 = ld4(&zs[(long)node * 64 + c]);

    int beg = rowptr[node];
    int end = rowptr[node + 1];
    for (int cb = beg; cb < end; cb += 64) {
        int cnt = min(64, end - cb);
        int cv = (lane < cnt) ? col[cb + lane] : 0;
        int full = cnt >> 2;
        int trips = (cnt + 3) >> 2;
        int t = 0;
        for (; t + 4 <= full; t += 4) {
            int j = slot + 4 * t;
            int s0 = __shfl(cv, j);
            int s1 = __shfl(cv, j + 4);
            int s2 = __shfl(cv, j + 8);
            int s3 = __shfl(cv, j + 12);
            float4 v0 = ld4(&zs[(long)s0 * 64 + c]);
            float4 v1 = ld4(&zs[(long)s1 * 64 + c]);
            float4 v2 = ld4(&zs[(long)s2 * 64 + c]);
            float4 v3 = ld4(&zs[(long)s3 * 64 + c]);
            acc4(a0, v0); acc4(a1, v1); acc4(a2, v2); acc4(a3, v3);
        }
        for (; t + 2 <= full; t += 2) {
            int j = slot + 4 * t;
            int s0 = __shfl(cv, j);
            int s1 = __shfl(cv, j + 4);
            float4 v0 = ld4(&zs[(long)s0 * 64 + c]);
            float4 v1 = ld4(&zs[(long)s1 * 64 + c]);
            acc4(a0, v0); acc4(a1, v1);
        }
        for (; t < trips; t++) {
            int j = slot + 4 * t;
            bool p = j < cnt;
            int s = __shfl(cv, p ? j : 0);
            if (p) acc4(a0, ld4(&zs[(long)s * 64 + c]));
        }
    }
    acc4(a0, a1); acc4(a2, a3); acc4(a0, a2);
    a0.x += __shfl_xor(a0.x, 16); a0.x += __shfl_xor(a0.x, 32);
    a0.y += __shfl_xor(a0.y, 16); a0.y += __shfl_xor(a0.y, 32);
    a0.z += __shfl_xor(a0.z, 16); a0.z += __shfl_xor(a0.z, 32);
    a0.w += __shfl_xor(a0.w, 16); a0.w += __shfl_xor(a0.w, 32);
    if (slot == 0) {
        float di = dinv[node];
        float4 bi = ld4(&bias[c]);
        a0.x = a0.x * di + bi.x;
        a0.y = a0.y * di + bi.y;
        a0.z = a0.z * di + bi.z;
        a0.w = a0.w * di + bi.w;
        ushort4 h, l;
        split_bf16(a0.x, h.x, l.x);
        split_bf16(a0.y, h.y, l.y);
        split_bf16(a0.z, h.z, l.z);
        split_bf16(a0.w, h.w, l.w);
        long o = tix(node, c, 64);
        *(ushort4*)&zhi[o] = h;
        *(ushort4*)&zlo[o] = l;
    }
}

// ---------------- launch ----------------

extern "C" void kernel_launch(void* const* d_in, const int* in_sizes, int n_in,
                              void* d_out, int out_size, void* d_ws, size_t ws_size,
                              hipStream_t stream) {
    const float* x        = (const float*)d_in[0];
    const int* ei         = (const int*)d_in[1];   // int32 (harness integer convention)
    const float* W1       = (const float*)d_in[2];
    const float* b1       = (const float*)d_in[3];
    const float* W2       = (const float*)d_in[4];
    const float* b2       = (const float*)d_in[5];
    const float* Wd1      = (const float*)d_in[6];
    const float* bd1      = (const float*)d_in[7];
    const float* Wd2      = (const float*)d_in[8];
    const float* bd2      = (const float*)d_in[9];
    float* out            = (float*)d_out;

    const int N = in_sizes[0] / IN_CH;   // 50000 (multiple of 16)
    const int E = in_sizes[1] / 2;       // 800000

    char* p = (char*)d_ws;
    auto alloc = [&](size_t bytes) {
        char* r = p;
        p += (bytes + 255) & ~(size_t)255;
        return r;
    };
    int*   counts    = (int*)  alloc((size_t)(N + 1) * 4);
    int*   rowptr    = (int*)  alloc((size_t)(N + 1) * 4);
    int*   nxt       = (int*)  alloc((size_t)N * 4);
    int*   blocksums = (int*)  alloc(256 * 4);
    int*   blockoffs = (int*)  alloc(256 * 4);
    float* dinv      = (float*)alloc((size_t)N * 4);
    int*   col       = (int*)  alloc((size_t)E * 4);
    float* xs        = (float*)alloc((size_t)N * IN_CH * 4);
    u16*   xa_hi     = (u16*)  alloc((size_t)N * IN_CH * 2);
    u16*   xa_lo     = (u16*)  alloc((size_t)N * IN_CH * 2);
    float* zs        = (float*)alloc((size_t)N * LATENT * 4);
    u16*   z_hi      = (u16*)  alloc((size_t)N * LATENT * 2);
    u16*   z_lo      = (u16*)  alloc((size_t)N * LATENT * 2);
    u16*   w1t_hi    = (u16*)  alloc((size_t)IN_CH * HIDDEN * 2);
    u16*   w1t_lo    = (u16*)  alloc((size_t)IN_CH * HIDDEN * 2);
    u16*   w2t_hi    = (u16*)  alloc((size_t)HIDDEN * LATENT * 2);
    u16*   w2t_lo    = (u16*)  alloc((size_t)HIDDEN * LATENT * 2);
    u16*   wd1t_hi   = (u16*)  alloc((size_t)LATENT * HIDDEN * 2);
    u16*   wd1t_lo   = (u16*)  alloc((size_t)LATENT * HIDDEN * 2);
    u16*   wd2t_hi   = (u16*)  alloc((size_t)HIDDEN * IN_CH * 2);
    u16*   wd2t_lo   = (u16*)  alloc((size_t)HIDDEN * IN_CH * 2);

    const int nblk = (N + 255) / 256;
    const int total4 = N * (IN_CH / 4);
    const int chunks = (E + 255) / 256;          // edge chunks of 256
    const int nper = (N + 7) / 8;                // dst-range width per partition

    hipMemsetAsync(counts, 0, (size_t)(N + 1) * 4, stream);
    hist_kernel<<<chunks * 8, 256, 0, stream>>>(ei, E, counts, nper);
    scan1_kernel<<<nblk, 256, 0, stream>>>(counts, rowptr, blocksums, dinv, N);
    scan2_kernel<<<1, 256, 0, stream>>>(blocksums, blockoffs, rowptr, nblk, N);
    scan3_prescale_kernel<<<(total4 + 255) / 256, 256, 0, stream>>>(
        rowptr, blockoffs, nxt, x, dinv, xs, N, total4);
    fill_kernel<<<chunks * 8, 256, 0, stream>>>(ei, E, nxt, col, nper);
    wsplit_all<<<384, 256, 0, stream>>>(W1, W2, Wd1, Wd2,
                                        w1t_hi, w1t_lo, w2t_hi, w2t_lo,
                                        wd1t_hi, wd1t_lo, wd2t_hi, wd2t_lo);

    // AGGX: xa = D^-1/2 A^ D^-1/2 X (tiled split out)
    aggx_kernel<<<(N + 3) / 4, 256, 0, stream>>>(xs, rowptr, col, dinv, xa_hi, xa_lo, N);

    const int fblk = (N + 31) / 32;  // 1563

    // enc_fused: zs = (relu(xa@W1+b1) @ W2) * dinv
    enc_fused<<<fblk, 256, 0, stream>>>(xa_hi, xa_lo, w1t_hi, w1t_lo,
                                        w2t_hi, w2t_lo, b1, dinv, zs, N);
    // AGG2: z = dinv*(sum zs) + b2 -> tiled split
    agg64_kernel<<<(N + 3) / 4, 256, 0, stream>>>(zs, rowptr, col, dinv, b2, z_hi, z_lo, N);
    // dec_fused: out = relu(z@Wd1+bd1) @ Wd2 + bd2
    dec_fused<<<fblk, 256, 0, stream>>>(z_hi, z_lo, wd1t_hi, wd1t_lo,
                                        wd2t_hi, wd2t_lo, bd1, bd2, out, N);
}

// Round 4
// 285.046 us; speedup vs baseline: 1.6363x; 1.1137x over previous
//
#include <hip/hip_runtime.h>

// GraphAE: 2x GCNConv encoder + 2-layer MLP decoder.
// N=50000, IN=128, HID=256, LAT=64, E=800000. fp32 in/out.
//
// R14 changes vs R13:
//  - f16 gather planes: xs and zs stored as _Float16 (12.8MB / 6.4MB).
//    R11/R13 established aggx is THROUGHPUT-bound on the L2-miss path
//    (FETCH pinned at 189MB = 8 XCDs x sizeof(xs), ~3.7 TB/s at any
//    occupancy/pipeline depth). Only byte reduction helps: f16 halves the
//    gathered bytes and the per-XCD L2 footprint. fp32 accumulate; f16
//    rounding adds ~1e-4 end-to-end (f16 mantissa 2^-11, GEMM-damped),
//    vs bf16 which would add ~1e-3.
//  - aggx back to R11 4-deep shape (R13 8-deep: no gain, occupancy drop).
//  - R11: hist/fill dst-range partitioned 8 ways (confirmed win).
// (R10: GEMM1+2 and GEMM3+4 fused via 32KB LDS frag tiles; R8: MFMA-frag-tiled
//  hi/lo bf16 planes, LDS-free coalesced frag loads.)

#define IN_CH  128
#define HIDDEN 256
#define LATENT 64

typedef unsigned short u16;
typedef unsigned int u32;
typedef __bf16 bf16x8 __attribute__((ext_vector_type(8)));
typedef float f32x4 __attribute__((ext_vector_type(4)));
typedef _Float16 f16x4 __attribute__((ext_vector_type(4)));

static __device__ __forceinline__ float4 ld4(const float* p) {
    return *reinterpret_cast<const float4*>(p);
}
static __device__ __forceinline__ void st4(float* p, float4 v) {
    *reinterpret_cast<float4*>(p) = v;
}
static __device__ __forceinline__ void acc4(float4& a, float4 v) {
    a.x += v.x; a.y += v.y; a.z += v.z; a.w += v.w;
}
static __device__ __forceinline__ f16x4 ldh4(const _Float16* p) {
    return *reinterpret_cast<const f16x4*>(p);
}
static __device__ __forceinline__ void acch(float4& a, f16x4 v) {
    a.x += (float)v[0]; a.y += (float)v[1]; a.z += (float)v[2]; a.w += (float)v[3];
}

// truncating hi/lo split: hi = top16(v); lo = top16(v - hi). v-hi exact.
static __device__ __forceinline__ void split_bf16(float v, u16& hi, u16& lo) {
    u32 b = __float_as_uint(v);
    hi = (u16)(b >> 16);
    float hf = __uint_as_float(b & 0xFFFF0000u);
    lo = (u16)(__float_as_uint(v - hf) >> 16);
}

// tiled-layout offset (elements). K multiple of 8; row tiles of 16.
static __device__ __forceinline__ long tix(int row, int k, int K) {
    return ((long)(row >> 4) * (K >> 3) + (k >> 3)) * 128 + ((row & 15) << 3) + (k & 7);
}

#define MFMA3(ACC, AH, AL, BH, BL)                                             \
    ACC = __builtin_amdgcn_mfma_f32_16x16x32_bf16(AH, BH, ACC, 0, 0, 0);       \
    ACC = __builtin_amdgcn_mfma_f32_16x16x32_bf16(AH, BL, ACC, 0, 0, 0);       \
    ACC = __builtin_amdgcn_mfma_f32_16x16x32_bf16(AL, BH, ACC, 0, 0, 0);

// ---------------- graph structure kernels ----------------

// Partitioned histogram: block b handles edge chunk (b>>3), dst range (b&7).
__global__ void hist_kernel(const int* __restrict__ ei, int E,
                            int* __restrict__ counts, int nper) {
    int part = blockIdx.x & 7;
    int e = (blockIdx.x >> 3) * 256 + threadIdx.x;
    if (e >= E) return;
    int d = ei[E + e];
    if ((unsigned)(d - part * nper) < (unsigned)nper) atomicAdd(&counts[d], 1);
}

// scan1 also emits dinv[i] = rsqrt(counts[i]+1)
__global__ void scan1_kernel(const int* __restrict__ counts, int* __restrict__ rowptr,
                             int* __restrict__ blocksums, float* __restrict__ dinv, int N) {
    __shared__ int sh[256];
    int tid = threadIdx.x;
    int i = blockIdx.x * 256 + tid;
    int v = (i < N) ? counts[i] : 0;
    if (i < N) dinv[i] = rsqrtf((float)v + 1.0f);
    sh[tid] = v;
    __syncthreads();
    for (int off = 1; off < 256; off <<= 1) {
        int t = (tid >= off) ? sh[tid - off] : 0;
        __syncthreads();
        sh[tid] += t;
        __syncthreads();
    }
    if (i < N) rowptr[i] = sh[tid] - v;
    if (tid == 255) blocksums[blockIdx.x] = sh[255];
}

__global__ void scan2_kernel(const int* __restrict__ blocksums, int* __restrict__ blockoffs,
                             int* __restrict__ rowptr, int nblk, int N) {
    __shared__ int sh[256];
    int tid = threadIdx.x;
    int v = (tid < nblk) ? blocksums[tid] : 0;
    sh[tid] = v;
    __syncthreads();
    for (int off = 1; off < 256; off <<= 1) {
        int t = (tid >= off) ? sh[tid - off] : 0;
        __syncthreads();
        sh[tid] += t;
        __syncthreads();
    }
    if (tid < nblk) blockoffs[tid] = sh[tid] - v;
    if (tid == nblk - 1) rowptr[N] = sh[tid];
}

// scan3 (finalize rowptr, init nxt) + prescale xs = dinv*x (f16), fused.
__global__ void scan3_prescale_kernel(
    int* __restrict__ rowptr, const int* __restrict__ blockoffs, int* __restrict__ next,
    const float* __restrict__ x, const float* __restrict__ dinv, _Float16* __restrict__ xsh,
    int N, int total4) {
    int i = blockIdx.x * 256 + threadIdx.x;
    if (i < N) {
        int r = rowptr[i] + blockoffs[i >> 8];
        rowptr[i] = r;
        next[i] = r;
    }
    if (i < total4) {
        float s = dinv[i >> 5];
        float4 v = ld4(&x[(long)i * 4]);
        f16x4 h;
        h[0] = (_Float16)(v.x * s);
        h[1] = (_Float16)(v.y * s);
        h[2] = (_Float16)(v.z * s);
        h[3] = (_Float16)(v.w * s);
        *reinterpret_cast<f16x4*>(&xsh[(long)i * 4]) = h;
    }
}

// Partitioned CSR fill: block b handles edge chunk (b>>3), dst range (b&7).
__global__ void fill_kernel(const int* __restrict__ ei, int E,
                            int* __restrict__ next, int* __restrict__ col, int nper) {
    int part = blockIdx.x & 7;
    int e = (blockIdx.x >> 3) * 256 + threadIdx.x;
    if (e >= E) return;
    int d = ei[E + e];
    if ((unsigned)(d - part * nper) < (unsigned)nper) {
        int s = ei[e];
        int pos = atomicAdd(&next[d], 1);
        col[pos] = s;
    }
}

// All four weights: W[K,N] fp32 -> transposed TILED hi/lo planes (rows=n).
__global__ void wsplit_all(
    const float* __restrict__ W1, const float* __restrict__ W2,
    const float* __restrict__ Wd1, const float* __restrict__ Wd2,
    u16* __restrict__ w1h, u16* __restrict__ w1l, u16* __restrict__ w2h, u16* __restrict__ w2l,
    u16* __restrict__ wd1h, u16* __restrict__ wd1l, u16* __restrict__ wd2h, u16* __restrict__ wd2l) {
    int idx = blockIdx.x * 256 + threadIdx.x;
    const float* W; u16 *H, *L; int K, N, base;
    if (idx < 32768)      { W = W1;  H = w1h;  L = w1l;  K = 128; N = 256; base = idx; }
    else if (idx < 49152) { W = W2;  H = w2h;  L = w2l;  K = 256; N = 64;  base = idx - 32768; }
    else if (idx < 65536) { W = Wd1; H = wd1h; L = wd1l; K = 64;  N = 256; base = idx - 49152; }
    else if (idx < 98304) { W = Wd2; H = wd2h; L = wd2l; K = 256; N = 128; base = idx - 65536; }
    else return;
    int k = base / N, n = base % N;
    u16 h, l;
    split_bf16(W[base], h, l);
    long o = tix(n, k, K);
    H[o] = h;
    L[o] = l;
}

// ---------------- fused encoder: zs = (relu(xa@W1+b1) @ W2) * dinv ----------------
__global__ __launch_bounds__(256) void enc_fused(
    const u16* __restrict__ xa_hi, const u16* __restrict__ xa_lo,
    const u16* __restrict__ w1h, const u16* __restrict__ w1l,
    const u16* __restrict__ w2h, const u16* __restrict__ w2l,
    const float* __restrict__ b1, const float* __restrict__ dinv,
    _Float16* __restrict__ zsh, int M) {
    __shared__ u16 o1[2][32 * 256];  // 32 KB

    const int tid = threadIdx.x;
    const int wid = tid >> 6, lane = tid & 63, quad = lane >> 4, lm = lane & 15;
    const int rt0 = blockIdx.x * 2;
    const int last_rt = (M >> 4) - 1;

    // ---- stage A: out1 = relu(xa @ W1 + b1), K=128 (KB=16, KC=4) ----
    f32x4 acc[2][4];
#pragma unroll
    for (int i = 0; i < 2; i++)
#pragma unroll
        for (int j = 0; j < 4; j++) acc[i][j] = (f32x4){0.f, 0.f, 0.f, 0.f};

#pragma unroll
    for (int kc = 0; kc < 4; kc++) {
        const int kb = kc * 4 + quad;
        bf16x8 ah[2], al[2], bh[4], bl[4];
#pragma unroll
        for (int i = 0; i < 2; i++) {
            int rt = rt0 + i; rt = rt <= last_rt ? rt : last_rt;
            long o = ((long)rt * 16 + kb) * 128 + lm * 8;
            ah[i] = *(const bf16x8*)&xa_hi[o];
            al[i] = *(const bf16x8*)&xa_lo[o];
        }
#pragma unroll
        for (int j = 0; j < 4; j++) {
            long o = ((long)(wid * 4 + j) * 16 + kb) * 128 + lm * 8;
            bh[j] = *(const bf16x8*)&w1h[o];
            bl[j] = *(const bf16x8*)&w1l[o];
        }
#pragma unroll
        for (int i = 0; i < 2; i++)
#pragma unroll
            for (int j = 0; j < 4; j++) { MFMA3(acc[i][j], ah[i], al[i], bh[j], bl[j]); }
    }

    // epilogue A -> LDS tiled (row in [0,32), k=coln in [0,256), KB=32)
#pragma unroll
    for (int i = 0; i < 2; i++)
#pragma unroll
        for (int j = 0; j < 4; j++) {
            int coln = wid * 64 + j * 16 + lm;
            float bi = b1[coln];
#pragma unroll
            for (int r = 0; r < 4; r++) {
                int row = i * 16 + quad * 4 + r;  // block-local
                float v = fmaxf(acc[i][j][r] + bi, 0.f);
                u16 h, l;
                split_bf16(v, h, l);
                int o = ((row >> 4) * 32 + (coln >> 3)) * 128 + ((row & 15) << 3) + (coln & 7);
                o1[0][o] = h;
                o1[1][o] = l;
            }
        }
    __syncthreads();

    // ---- stage B: zs = (out1 @ W2) * dinv, K=256 (KB=32, KC=8), 16 cols/wave ----
    f32x4 acc2[2];
    acc2[0] = (f32x4){0.f, 0.f, 0.f, 0.f};
    acc2[1] = (f32x4){0.f, 0.f, 0.f, 0.f};
#pragma unroll
    for (int kc = 0; kc < 8; kc++) {
        const int kb = kc * 4 + quad;
        bf16x8 ah[2], al[2], bh, bl;
#pragma unroll
        for (int i = 0; i < 2; i++) {
            int o = (i * 32 + kb) * 128 + lm * 8;
            ah[i] = *(const bf16x8*)&o1[0][o];
            al[i] = *(const bf16x8*)&o1[1][o];
        }
        {
            long o = ((long)wid * 32 + kb) * 128 + lm * 8;
            bh = *(const bf16x8*)&w2h[o];
            bl = *(const bf16x8*)&w2l[o];
        }
#pragma unroll
        for (int i = 0; i < 2; i++) { MFMA3(acc2[i], ah[i], al[i], bh, bl); }
    }
#pragma unroll
    for (int i = 0; i < 2; i++) {
        int coln = wid * 16 + lm;
#pragma unroll
        for (int r = 0; r < 4; r++) {
            int row = rt0 * 16 + i * 16 + quad * 4 + r;
            if (row < M) zsh[(long)row * 64 + coln] = (_Float16)(acc2[i][r] * dinv[row]);
        }
    }
}

// ---------------- fused decoder: out = relu(z@Wd1+bd1)@Wd2 + bd2 ----------------
__global__ __launch_bounds__(256) void dec_fused(
    const u16* __restrict__ z_hi, const u16* __restrict__ z_lo,
    const u16* __restrict__ wd1h, const u16* __restrict__ wd1l,
    const u16* __restrict__ wd2h, const u16* __restrict__ wd2l,
    const float* __restrict__ bd1, const float* __restrict__ bd2,
    float* __restrict__ out, int M) {
    __shared__ u16 dsm[2][32 * 256];  // 32 KB

    const int tid = threadIdx.x;
    const int wid = tid >> 6, lane = tid & 63, quad = lane >> 4, lm = lane & 15;
    const int rt0 = blockIdx.x * 2;
    const int last_rt = (M >> 4) - 1;

    // ---- stage A: d = relu(z @ Wd1 + bd1), K=64 (KB=8, KC=2) ----
    f32x4 acc[2][4];
#pragma unroll
    for (int i = 0; i < 2; i++)
#pragma unroll
        for (int j = 0; j < 4; j++) acc[i][j] = (f32x4){0.f, 0.f, 0.f, 0.f};

#pragma unroll
    for (int kc = 0; kc < 2; kc++) {
        const int kb = kc * 4 + quad;
        bf16x8 ah[2], al[2], bh[4], bl[4];
#pragma unroll
        for (int i = 0; i < 2; i++) {
            int rt = rt0 + i; rt = rt <= last_rt ? rt : last_rt;
            long o = ((long)rt * 8 + kb) * 128 + lm * 8;
            ah[i] = *(const bf16x8*)&z_hi[o];
            al[i] = *(const bf16x8*)&z_lo[o];
        }
#pragma unroll
        for (int j = 0; j < 4; j++) {
            long o = ((long)(wid * 4 + j) * 8 + kb) * 128 + lm * 8;
            bh[j] = *(const bf16x8*)&wd1h[o];
            bl[j] = *(const bf16x8*)&wd1l[o];
        }
#pragma unroll
        for (int i = 0; i < 2; i++)
#pragma unroll
            for (int j = 0; j < 4; j++) { MFMA3(acc[i][j], ah[i], al[i], bh[j], bl[j]); }
    }

    // epilogue A -> LDS tiled
#pragma unroll
    for (int i = 0; i < 2; i++)
#pragma unroll
        for (int j = 0; j < 4; j++) {
            int coln = wid * 64 + j * 16 + lm;
            float bi = bd1[coln];
#pragma unroll
            for (int r = 0; r < 4; r++) {
                int row = i * 16 + quad * 4 + r;
                float v = fmaxf(acc[i][j][r] + bi, 0.f);
                u16 h, l;
                split_bf16(v, h, l);
                int o = ((row >> 4) * 32 + (coln >> 3)) * 128 + ((row & 15) << 3) + (coln & 7);
                dsm[0][o] = h;
                dsm[1][o] = l;
            }
        }
    __syncthreads();

    // ---- stage B: out = d @ Wd2 + bd2, K=256 (KB=32, KC=8), 32 cols/wave ----
    f32x4 acc2[2][2];
#pragma unroll
    for (int i = 0; i < 2; i++)
#pragma unroll
        for (int j = 0; j < 2; j++) acc2[i][j] = (f32x4){0.f, 0.f, 0.f, 0.f};
#pragma unroll
    for (int kc = 0; kc < 8; kc++) {
        const int kb = kc * 4 + quad;
        bf16x8 ah[2], al[2], bh[2], bl[2];
#pragma unroll
        for (int i = 0; i < 2; i++) {
            int o = (i * 32 + kb) * 128 + lm * 8;
            ah[i] = *(const bf16x8*)&dsm[0][o];
            al[i] = *(const bf16x8*)&dsm[1][o];
        }
#pragma unroll
        for (int j = 0; j < 2; j++) {
            long o = ((long)(wid * 2 + j) * 32 + kb) * 128 + lm * 8;
            bh[j] = *(const bf16x8*)&wd2h[o];
            bl[j] = *(const bf16x8*)&wd2l[o];
        }
#pragma unroll
        for (int i = 0; i < 2; i++)
#pragma unroll
            for (int j = 0; j < 2; j++) { MFMA3(acc2[i][j], ah[i], al[i], bh[j], bl[j]); }
    }
#pragma unroll
    for (int i = 0; i < 2; i++)
#pragma unroll
        for (int j = 0; j < 2; j++) {
            int coln = wid * 32 + j * 16 + lm;
            float bi = bd2[coln];
#pragma unroll
            for (int r = 0; r < 4; r++) {
                int row = rt0 * 16 + i * 16 + quad * 4 + r;
                if (row < M) out[(long)row * 128 + coln] = acc2[i][j][r] + bi;
            }
        }
}

// ---------------- aggregation kernels ----------------

// AGGX: xa[i] = dinv[i]*(xs[i] + sum_in xs[s]); f16 gather (256B rows),
// fp32 accumulate; writes TILED hi/lo planes. Wave = 1 node, 2 edge-slots x
// 32 lanes x 8B. 4-deep load pipeline.
__global__ __launch_bounds__(256) void aggx_kernel(
    const _Float16* __restrict__ xsh, const int* __restrict__ rowptr,
    const int* __restrict__ col, const float* __restrict__ dinv,
    u16* __restrict__ xahi, u16* __restrict__ xalo, int N) {
    int wid = threadIdx.x >> 6;
    int lane = threadIdx.x & 63;
    int node = blockIdx.x * 4 + wid;
    if (node >= N) return;
    int slot = lane >> 5;
    int c = (lane & 31) * 4;  // channel offset (4 f16 = 8B per lane)

    float4 a0 = make_float4(0.f, 0.f, 0.f, 0.f);
    float4 a1 = a0, a2 = a0, a3 = a0;
    if (slot == 0) acch(a0, ldh4(&xsh[(long)node * 128 + c]));

    int beg = rowptr[node];
    int end = rowptr[node + 1];
    for (int cb = beg; cb < end; cb += 64) {
        int cnt = min(64, end - cb);
        int cv = (lane < cnt) ? col[cb + lane] : 0;
        int full = cnt >> 1;
        int trips = (cnt + 1) >> 1;
        int t = 0;
        for (; t + 4 <= full; t += 4) {
            int j = slot + 2 * t;
            int s0 = __shfl(cv, j);
            int s1 = __shfl(cv, j + 2);
            int s2 = __shfl(cv, j + 4);
            int s3 = __shfl(cv, j + 6);
            f16x4 v0 = ldh4(&xsh[(long)s0 * 128 + c]);
            f16x4 v1 = ldh4(&xsh[(long)s1 * 128 + c]);
            f16x4 v2 = ldh4(&xsh[(long)s2 * 128 + c]);
            f16x4 v3 = ldh4(&xsh[(long)s3 * 128 + c]);
            acch(a0, v0); acch(a1, v1); acch(a2, v2); acch(a3, v3);
        }
        for (; t < trips; t++) {
            int j = slot + 2 * t;
            bool p = j < cnt;
            int s = __shfl(cv, p ? j : 0);
            if (p) acch(a0, ldh4(&xsh[(long)s * 128 + c]));
        }
    }
    acc4(a0, a1); acc4(a2, a3); acc4(a0, a2);
    a0.x += __shfl_xor(a0.x, 32);
    a0.y += __shfl_xor(a0.y, 32);
    a0.z += __shfl_xor(a0.z, 32);
    a0.w += __shfl_xor(a0.w, 32);
    if (slot == 0) {
        float di = dinv[node];
        a0.x *= di; a0.y *= di; a0.z *= di; a0.w *= di;
        ushort4 h, l;
        split_bf16(a0.x, h.x, l.x);
        split_bf16(a0.y, h.y, l.y);
        split_bf16(a0.z, h.z, l.z);
        split_bf16(a0.w, h.w, l.w);
        long o = tix(node, c, 128);
        *(ushort4*)&xahi[o] = h;
        *(ushort4*)&xalo[o] = l;
    }
}

// AGG2: z[i] = dinv[i]*(zs[i] + sum_in zs[s]) + b2; f16 gather (128B rows),
// fp32 accumulate; writes TILED hi/lo planes. Wave = 1 node, 4 edge-slots x
// 16 lanes x 8B. 4-deep pipeline.
__global__ __launch_bounds__(256) void agg64_kernel(
    const _Float16* __restrict__ zsh, const int* __restrict__ rowptr,
    const int* __restrict__ col, const float* __restrict__ dinv,
    const float* __restrict__ bias,
    u16* __restrict__ zhi, u16* __restrict__ zlo, int N) {
    int wid = threadIdx.x >> 6;
    int lane = threadIdx.x & 63;
    int node = blockIdx.x * 4 + wid;
    if (node >= N) return;
    int slot = lane >> 4;
    int c = (lane & 15) * 4;  // channel offset (4 f16 = 8B per lane)

    float4 a0 = make_float4(0.f, 0.f, 0.f, 0.f);
    float4 a1 = a0, a2 = a0, a3 = a0;
    if (slot == 0) acch(a0, ldh4(&zsh[(long)node * 64 + c]));

    int beg = rowptr[node];
    int end = rowptr[node + 1];
    for (int cb = beg; cb < end; cb += 64) {
        int cnt = min(64, end - cb);
        int cv = (lane < cnt) ? col[cb + lane] : 0;
        int full = cnt >> 2;
        int trips = (cnt + 3) >> 2;
        int t = 0;
        for (; t + 4 <= full; t += 4) {
            int j = slot + 4 * t;
            int s0 = __shfl(cv, j);
            int s1 = __shfl(cv, j + 4);
            int s2 = __shfl(cv, j + 8);
            int s3 = __shfl(cv, j + 12);
            f16x4 v0 = ldh4(&zsh[(long)s0 * 64 + c]);
            f16x4 v1 = ldh4(&zsh[(long)s1 * 64 + c]);
            f16x4 v2 = ldh4(&zsh[(long)s2 * 64 + c]);
            f16x4 v3 = ldh4(&zsh[(long)s3 * 64 + c]);
            acch(a0, v0); acch(a1, v1); acch(a2, v2); acch(a3, v3);
        }
        for (; t < trips; t++) {
            int j = slot + 4 * t;
            bool p = j < cnt;
            int s = __shfl(cv, p ? j : 0);
            if (p) acch(a0, ldh4(&zsh[(long)s * 64 + c]));
        }
    }
    acc4(a0, a1); acc4(a2, a3); acc4(a0, a2);
    a0.x += __shfl_xor(a0.x, 16); a0.x += __shfl_xor(a0.x, 32);
    a0.y += __shfl_xor(a0.y, 16); a0.y += __shfl_xor(a0.y, 32);
    a0.z += __shfl_xor(a0.z, 16); a0.z += __shfl_xor(a0.z, 32);
    a0.w += __shfl_xor(a0.w, 16); a0.w += __shfl_xor(a0.w, 32);
    if (slot == 0) {
        float di = dinv[node];
        float4 bi = ld4(&bias[c]);
        a0.x = a0.x * di + bi.x;
        a0.y = a0.y * di + bi.y;
        a0.z = a0.z * di + bi.z;
        a0.w = a0.w * di + bi.w;
        ushort4 h, l;
        split_bf16(a0.x, h.x, l.x);
        split_bf16(a0.y, h.y, l.y);
        split_bf16(a0.z, h.z, l.z);
        split_bf16(a0.w, h.w, l.w);
        long o = tix(node, c, 64);
        *(ushort4*)&zhi[o] = h;
        *(ushort4*)&zlo[o] = l;
    }
}

// ---------------- launch ----------------

extern "C" void kernel_launch(void* const* d_in, const int* in_sizes, int n_in,
                              void* d_out, int out_size, void* d_ws, size_t ws_size,
                              hipStream_t stream) {
    const float* x        = (const float*)d_in[0];
    const int* ei         = (const int*)d_in[1];   // int32 (harness integer convention)
    const float* W1       = (const float*)d_in[2];
    const float* b1       = (const float*)d_in[3];
    const float* W2       = (const float*)d_in[4];
    const float* b2       = (const float*)d_in[5];
    const float* Wd1      = (const float*)d_in[6];
    const float* bd1      = (const float*)d_in[7];
    const float* Wd2      = (const float*)d_in[8];
    const float* bd2      = (const float*)d_in[9];
    float* out            = (float*)d_out;

    const int N = in_sizes[0] / IN_CH;   // 50000 (multiple of 16)
    const int E = in_sizes[1] / 2;       // 800000

    char* p = (char*)d_ws;
    auto alloc = [&](size_t bytes) {
        char* r = p;
        p += (bytes + 255) & ~(size_t)255;
        return r;
    };
    int*      counts    = (int*)     alloc((size_t)(N + 1) * 4);
    int*      rowptr    = (int*)     alloc((size_t)(N + 1) * 4);
    int*      nxt       = (int*)     alloc((size_t)N * 4);
    int*      blocksums = (int*)     alloc(256 * 4);
    int*      blockoffs = (int*)     alloc(256 * 4);
    float*    dinv      = (float*)   alloc((size_t)N * 4);
    int*      col       = (int*)     alloc((size_t)E * 4);
    _Float16* xsh       = (_Float16*)alloc((size_t)N * IN_CH * 2);
    u16*      xa_hi     = (u16*)     alloc((size_t)N * IN_CH * 2);
    u16*      xa_lo     = (u16*)     alloc((size_t)N * IN_CH * 2);
    _Float16* zsh       = (_Float16*)alloc((size_t)N * LATENT * 2);
    u16*      z_hi      = (u16*)     alloc((size_t)N * LATENT * 2);
    u16*      z_lo      = (u16*)     alloc((size_t)N * LATENT * 2);
    u16*      w1t_hi    = (u16*)     alloc((size_t)IN_CH * HIDDEN * 2);
    u16*      w1t_lo    = (u16*)     alloc((size_t)IN_CH * HIDDEN * 2);
    u16*      w2t_hi    = (u16*)     alloc((size_t)HIDDEN * LATENT * 2);
    u16*      w2t_lo    = (u16*)     alloc((size_t)HIDDEN * LATENT * 2);
    u16*      wd1t_hi   = (u16*)     alloc((size_t)LATENT * HIDDEN * 2);
    u16*      wd1t_lo   = (u16*)     alloc((size_t)LATENT * HIDDEN * 2);
    u16*      wd2t_hi   = (u16*)     alloc((size_t)HIDDEN * IN_CH * 2);
    u16*      wd2t_lo   = (u16*)     alloc((size_t)HIDDEN * IN_CH * 2);

    const int nblk = (N + 255) / 256;
    const int total4 = N * (IN_CH / 4);
    const int chunks = (E + 255) / 256;          // edge chunks of 256
    const int nper = (N + 7) / 8;                // dst-range width per partition

    hipMemsetAsync(counts, 0, (size_t)(N + 1) * 4, stream);
    hist_kernel<<<chunks * 8, 256, 0, stream>>>(ei, E, counts, nper);
    scan1_kernel<<<nblk, 256, 0, stream>>>(counts, rowptr, blocksums, dinv, N);
    scan2_kernel<<<1, 256, 0, stream>>>(blocksums, blockoffs, rowptr, nblk, N);
    scan3_prescale_kernel<<<(total4 + 255) / 256, 256, 0, stream>>>(
        rowptr, blockoffs, nxt, x, dinv, xsh, N, total4);
    fill_kernel<<<chunks * 8, 256, 0, stream>>>(ei, E, nxt, col, nper);
    wsplit_all<<<384, 256, 0, stream>>>(W1, W2, Wd1, Wd2,
                                        w1t_hi, w1t_lo, w2t_hi, w2t_lo,
                                        wd1t_hi, wd1t_lo, wd2t_hi, wd2t_lo);

    // AGGX: xa = D^-1/2 A^ D^-1/2 X (f16 gather, tiled split out)
    aggx_kernel<<<(N + 3) / 4, 256, 0, stream>>>(xsh, rowptr, col, dinv, xa_hi, xa_lo, N);

    const int fblk = (N + 31) / 32;  // 1563

    // enc_fused: zs = (relu(xa@W1+b1) @ W2) * dinv  (f16 out)
    enc_fused<<<fblk, 256, 0, stream>>>(xa_hi, xa_lo, w1t_hi, w1t_lo,
                                        w2t_hi, w2t_lo, b1, dinv, zsh, N);
    // AGG2: z = dinv*(sum zs) + b2 -> tiled split (f16 gather)
    agg64_kernel<<<(N + 3) / 4, 256, 0, stream>>>(zsh, rowptr, col, dinv, b2, z_hi, z_lo, N);
    // dec_fused: out = relu(z@Wd1+bd1) @ Wd2 + bd2
    dec_fused<<<fblk, 256, 0, stream>>>(z_hi, z_lo, wd1t_hi, wd1t_lo,
                                        wd2t_hi, wd2t_lo, bd1, bd2, out, N);
}